// Round 1
// baseline (507.449 us; speedup 1.0000x reference)
//
#include <hip/hip_runtime.h>
#include <hip/hip_bf16.h>
#include <stdint.h>

#define B_ 32
#define N_ 1024
#define D_ 1024

typedef __bf16 bf16x8 __attribute__((ext_vector_type(8)));
typedef float f32x4 __attribute__((ext_vector_type(4)));

static __device__ __forceinline__ unsigned short f2bf(float f) {
    union { float f; unsigned u; } v; v.f = f;
    unsigned r = v.u + 0x7fffu + ((v.u >> 16) & 1u);   // round-to-nearest-even
    return (unsigned short)(r >> 16);
}

static __device__ __forceinline__ void gld_lds16(const void* g, void* l) {
    __builtin_amdgcn_global_load_lds(
        (const __attribute__((address_space(1))) void*)g,
        (__attribute__((address_space(3))) void*)l, 16, 0, 0);
}

// ---------------------------------------------------------------------------
// K1: per-row softmax stats. x[row][0..1023] -> pb=bf16(softmax), xb=bf16(x),
// lse[row] = max + log(sum exp(x-max)).
// ---------------------------------------------------------------------------
__global__ __launch_bounds__(256) void prep_kernel(const float* __restrict__ x,
        unsigned short* __restrict__ pb, unsigned short* __restrict__ xb,
        float* __restrict__ lse) {
    int row = blockIdx.x;                     // 0..B*N-1
    const float4* xr = (const float4*)(x + (size_t)row * D_);
    int t = threadIdx.x;
    float4 v = xr[t];

    float m = fmaxf(fmaxf(v.x, v.y), fmaxf(v.z, v.w));
    for (int o = 32; o > 0; o >>= 1) m = fmaxf(m, __shfl_xor(m, o, 64));
    __shared__ float redm[4];
    __shared__ float reds[4];
    int wave = t >> 6, lane = t & 63;
    if (lane == 0) redm[wave] = m;
    __syncthreads();
    m = fmaxf(fmaxf(redm[0], redm[1]), fmaxf(redm[2], redm[3]));

    float e0 = expf(v.x - m), e1 = expf(v.y - m);
    float e2 = expf(v.z - m), e3 = expf(v.w - m);
    float s = e0 + e1 + e2 + e3;
    for (int o = 32; o > 0; o >>= 1) s += __shfl_xor(s, o, 64);
    if (lane == 0) reds[wave] = s;
    __syncthreads();
    s = reds[0] + reds[1] + reds[2] + reds[3];
    float inv = 1.0f / s;

    ushort4 pu, xu;
    pu.x = f2bf(e0 * inv); pu.y = f2bf(e1 * inv);
    pu.z = f2bf(e2 * inv); pu.w = f2bf(e3 * inv);
    xu.x = f2bf(v.x); xu.y = f2bf(v.y); xu.z = f2bf(v.z); xu.w = f2bf(v.w);
    ((ushort4*)(pb + (size_t)row * D_))[t] = pu;
    ((ushort4*)(xb + (size_t)row * D_))[t] = xu;
    if (t == 0) lse[row] = m + logf(s);
}

// ---------------------------------------------------------------------------
// K2/K5: batched bf16 GEMM, C[m][n] = sum_k A[m][k]*B[n][k] (- bias[n]).
// A,B row-major [1024][1024] bf16 per batch; C fp32. 128x128 tile, BK=32,
// 4 waves in 2x2, each wave 64x64 via 4x4 mfma_f32_16x16x32_bf16.
// Staging via global_load_lds width-16 (wave-uniform base + lane*16).
// ---------------------------------------------------------------------------
__global__ __launch_bounds__(256) void gemm_bt(const unsigned short* __restrict__ Ag,
        const unsigned short* __restrict__ Bg, float* __restrict__ Cg,
        const float* __restrict__ bias) {
    const int K = 1024;
    int b = blockIdx.z;
    const unsigned short* A  = Ag + (size_t)b * N_ * K;
    const unsigned short* Bm = Bg + (size_t)b * N_ * K;
    float* C = Cg + (size_t)b * (size_t)N_ * N_;
    int m0 = blockIdx.y * 128, n0 = blockIdx.x * 128;

    __shared__ unsigned short lds[2][128 * 32];   // A tile, B tile: 8 KB each
    int t = threadIdx.x;
    int wave = t >> 6, lane = t & 63;
    int wr = wave >> 1, wc = wave & 1;

    f32x4 acc[4][4];
    #pragma unroll
    for (int i = 0; i < 4; i++)
        #pragma unroll
        for (int j = 0; j < 4; j++)
            #pragma unroll
            for (int r = 0; r < 4; r++) acc[i][j][r] = 0.0f;

    int fm = lane & 15;            // m (or n) within 16
    int fk = (lane >> 4) * 8;      // k offset within 32

    for (int k0 = 0; k0 < K; k0 += 32) {
        __syncthreads();
        #pragma unroll
        for (int h = 0; h < 2; h++) {
            int c = h * 256 + t;            // chunk id; lds byte offset = c*16
            int r = c >> 2, col = (c & 3) * 8;
            gld_lds16(A  + (size_t)(m0 + r) * K + k0 + col, (char*)&lds[0][0] + c * 16);
            gld_lds16(Bm + (size_t)(n0 + r) * K + k0 + col, (char*)&lds[1][0] + c * 16);
        }
        __syncthreads();

        bf16x8 av[4], bv[4];
        #pragma unroll
        for (int i = 0; i < 4; i++) {
            av[i] = *(const bf16x8*)&lds[0][(wr * 64 + i * 16 + fm) * 32 + fk];
            bv[i] = *(const bf16x8*)&lds[1][(wc * 64 + i * 16 + fm) * 32 + fk];
        }
        #pragma unroll
        for (int i = 0; i < 4; i++)
            #pragma unroll
            for (int j = 0; j < 4; j++)
                acc[i][j] = __builtin_amdgcn_mfma_f32_16x16x32_bf16(av[i], bv[j], acc[i][j], 0, 0, 0);
    }

    // epilogue: C/D layout col=lane&15, row=(lane>>4)*4+reg
    int cr = (lane >> 4) * 4;
    int cc = lane & 15;
    #pragma unroll
    for (int i = 0; i < 4; i++) {
        int row = m0 + wr * 64 + i * 16 + cr;
        #pragma unroll
        for (int j = 0; j < 4; j++) {
            int col = n0 + wc * 64 + j * 16 + cc;
            float bvv = bias ? bias[b * N_ + col] : 0.0f;
            #pragma unroll
            for (int r = 0; r < 4; r++)
                C[(size_t)(row + r) * N_ + col] = acc[i][j][r] - bvv;
        }
    }
}

// ---------------------------------------------------------------------------
// K3: row softmax of S (fp32) -> attn (bf16)
// ---------------------------------------------------------------------------
__global__ __launch_bounds__(256) void softmax_kernel(const float* __restrict__ S,
        unsigned short* __restrict__ attn) {
    size_t row = blockIdx.x;
    const float4* sr = (const float4*)(S + row * N_);
    int t = threadIdx.x;
    float4 v = sr[t];

    float m = fmaxf(fmaxf(v.x, v.y), fmaxf(v.z, v.w));
    for (int o = 32; o > 0; o >>= 1) m = fmaxf(m, __shfl_xor(m, o, 64));
    __shared__ float redm[4];
    __shared__ float reds[4];
    int wave = t >> 6, lane = t & 63;
    if (lane == 0) redm[wave] = m;
    __syncthreads();
    m = fmaxf(fmaxf(redm[0], redm[1]), fmaxf(redm[2], redm[3]));

    float e0 = expf(v.x - m), e1 = expf(v.y - m);
    float e2 = expf(v.z - m), e3 = expf(v.w - m);
    float s = e0 + e1 + e2 + e3;
    for (int o = 32; o > 0; o >>= 1) s += __shfl_xor(s, o, 64);
    if (lane == 0) reds[wave] = s;
    __syncthreads();
    s = reds[0] + reds[1] + reds[2] + reds[3];
    float inv = 1.0f / s;

    ushort4 o4;
    o4.x = f2bf(e0 * inv); o4.y = f2bf(e1 * inv);
    o4.z = f2bf(e2 * inv); o4.w = f2bf(e3 * inv);
    ((ushort4*)(attn + row * N_))[t] = o4;
}

// ---------------------------------------------------------------------------
// K4: bf16 transpose per batch: xb[b][j][d] -> xbT[b][d][j], 64x64 tiles
// ---------------------------------------------------------------------------
__global__ __launch_bounds__(256) void transpose_kernel(const unsigned short* __restrict__ in,
        unsigned short* __restrict__ out) {
    int b  = blockIdx.z;
    int j0 = blockIdx.y * 64;
    int d0 = blockIdx.x * 64;
    __shared__ unsigned short tile[64][72];
    const unsigned short* ip = in + ((size_t)b * N_ + j0) * D_ + d0;
    int t = threadIdx.x;
    #pragma unroll
    for (int c = t; c < 512; c += 256) {
        int r = c >> 3, col = (c & 7) * 8;
        uint4 val = *(const uint4*)(ip + (size_t)r * D_ + col);
        *(uint4*)&tile[r][col] = val;
    }
    __syncthreads();
    unsigned short* op = out + ((size_t)b * D_ + d0) * N_ + j0;
    #pragma unroll
    for (int c = t; c < 512; c += 256) {
        int r = c >> 3, col = (c & 7) * 8;   // r = d within tile, col = j offset
        unsigned short vals[8];
        #pragma unroll
        for (int k = 0; k < 8; k++) vals[k] = tile[col + k][r];
        uint4 o;
        o.x = (unsigned)vals[0] | ((unsigned)vals[1] << 16);
        o.y = (unsigned)vals[2] | ((unsigned)vals[3] << 16);
        o.z = (unsigned)vals[4] | ((unsigned)vals[5] << 16);
        o.w = (unsigned)vals[6] | ((unsigned)vals[7] << 16);
        *(uint4*)(op + (size_t)r * N_ + col) = o;
    }
}

extern "C" void kernel_launch(void* const* d_in, const int* in_sizes, int n_in,
                              void* d_out, int out_size, void* d_ws, size_t ws_size,
                              hipStream_t stream) {
    const float* x = (const float*)d_in[0];
    float* out = (float*)d_out;
    char* ws = (char*)d_ws;

    // layout: [pb 64MB][xb 64MB][lse 128KB(+pad)][Sraw 128MB / xbT reuses it]
    unsigned short* pb   = (unsigned short*)(ws);
    unsigned short* xb   = (unsigned short*)(ws + 67108864ULL);
    float*          lse  = (float*)(ws + 134217728ULL);
    float*          Sraw = (float*)(ws + 135266304ULL);
    unsigned short* xbT  = (unsigned short*)Sraw;   // reused after softmax
    unsigned short* attn = pb;                      // pb dead after gemm1

    prep_kernel<<<dim3(B_ * N_), 256, 0, stream>>>(x, pb, xb, lse);
    gemm_bt<<<dim3(8, 8, B_), 256, 0, stream>>>(pb, xb, Sraw, lse);
    softmax_kernel<<<dim3(B_ * N_), 256, 0, stream>>>(Sraw, attn);
    transpose_kernel<<<dim3(16, 16, B_), 256, 0, stream>>>(xb, xbT);
    gemm_bt<<<dim3(8, 8, B_), 256, 0, stream>>>(attn, xbT, out, nullptr);
}

// Round 2
// 480.934 us; speedup vs baseline: 1.0551x; 1.0551x over previous
//
#include <hip/hip_runtime.h>
#include <hip/hip_bf16.h>
#include <stdint.h>

#define B_ 32
#define N_ 1024
#define D_ 1024

typedef __bf16 bf16x8 __attribute__((ext_vector_type(8)));
typedef float f32x4 __attribute__((ext_vector_type(4)));

static __device__ __forceinline__ unsigned short f2bf(float f) {
    union { float f; unsigned u; } v; v.f = f;
    unsigned r = v.u + 0x7fffu + ((v.u >> 16) & 1u);   // round-to-nearest-even
    return (unsigned short)(r >> 16);
}

static __device__ __forceinline__ void gld_lds16(const void* g, void* l) {
    __builtin_amdgcn_global_load_lds(
        (const __attribute__((address_space(1))) void*)g,
        (__attribute__((address_space(3))) void*)l, 16, 0, 0);
}

// ---------------------------------------------------------------------------
// K1: wave-per-row softmax stats. 4 rows/block, no __syncthreads.
// pb = bf16(softmax(x)), xb = bf16(x), lse = max + log(sum exp(x-max)).
// Lane l handles columns {4l+256q+0..3, q=0..3} — all loads/stores coalesced.
// ---------------------------------------------------------------------------
__global__ __launch_bounds__(256) void prep_kernel(const float* __restrict__ x,
        unsigned short* __restrict__ pb, unsigned short* __restrict__ xb,
        float* __restrict__ lse) {
    int row  = blockIdx.x * 4 + (threadIdx.x >> 6);
    int lane = threadIdx.x & 63;
    const float4* xr = (const float4*)(x + (size_t)row * D_);

    float4 v[4];
    #pragma unroll
    for (int q = 0; q < 4; q++) v[q] = xr[lane + 64 * q];

    float m = -1e30f;
    #pragma unroll
    for (int q = 0; q < 4; q++)
        m = fmaxf(m, fmaxf(fmaxf(v[q].x, v[q].y), fmaxf(v[q].z, v[q].w)));
    #pragma unroll
    for (int o = 1; o < 64; o <<= 1) m = fmaxf(m, __shfl_xor(m, o, 64));

    float4 e[4];
    float s = 0.0f;
    #pragma unroll
    for (int q = 0; q < 4; q++) {
        e[q].x = __expf(v[q].x - m); e[q].y = __expf(v[q].y - m);
        e[q].z = __expf(v[q].z - m); e[q].w = __expf(v[q].w - m);
        s += e[q].x + e[q].y + e[q].z + e[q].w;
    }
    #pragma unroll
    for (int o = 1; o < 64; o <<= 1) s += __shfl_xor(s, o, 64);
    float inv = 1.0f / s;

    ushort4* pr = (ushort4*)(pb + (size_t)row * D_);
    ushort4* xw = (ushort4*)(xb + (size_t)row * D_);
    #pragma unroll
    for (int q = 0; q < 4; q++) {
        ushort4 pu, xu;
        pu.x = f2bf(e[q].x * inv); pu.y = f2bf(e[q].y * inv);
        pu.z = f2bf(e[q].z * inv); pu.w = f2bf(e[q].w * inv);
        xu.x = f2bf(v[q].x); xu.y = f2bf(v[q].y);
        xu.z = f2bf(v[q].z); xu.w = f2bf(v[q].w);
        pr[lane + 64 * q] = pu;
        xw[lane + 64 * q] = xu;
    }
    if (lane == 0) lse[row] = m + logf(s);
}

// ---------------------------------------------------------------------------
// K2/K4: batched bf16 GEMM, C[m][n] = sum_k A[m][k]*B[n][k], fused epilogues.
// MODE 0 (gemm1): e = exp(acc - lse[col]) -> bf16 store + rowsum atomics.
// MODE 1 (gemm2): out = acc / rowsum[row], fp32 store.
// 128x128 tile, BK=32, 4 waves 2x2, 64x64/wave via 4x4 mfma_f32_16x16x32_bf16.
// LDS k-group XOR swizzle (g ^= (row>>1)&3) -> conflict-free ds_read_b128.
// ---------------------------------------------------------------------------
template<int MODE>
__global__ __launch_bounds__(256) void gemm_bt(const unsigned short* __restrict__ Ag,
        const unsigned short* __restrict__ Bg, void* __restrict__ Cg,
        const float* __restrict__ lse, float* __restrict__ rowsum) {
    const int K = 1024;
    int b = blockIdx.z;
    const unsigned short* A  = Ag + (size_t)b * N_ * K;
    const unsigned short* Bm = Bg + (size_t)b * N_ * K;
    int m0 = blockIdx.y * 128, n0 = blockIdx.x * 128;

    __shared__ unsigned short lds[2][128 * 32];   // 8 KB each
    int t = threadIdx.x;
    int wave = t >> 6, lane = t & 63;
    int wr = wave >> 1, wc = wave & 1;

    f32x4 acc[4][4];
    #pragma unroll
    for (int i = 0; i < 4; i++)
        #pragma unroll
        for (int j = 0; j < 4; j++)
            #pragma unroll
            for (int r = 0; r < 4; r++) acc[i][j][r] = 0.0f;

    int fm = lane & 15;            // m (or n) within 16
    int gf = lane >> 4;            // k-group 0..3 (8 elements each)

    for (int k0 = 0; k0 < K; k0 += 32) {
        __syncthreads();
        #pragma unroll
        for (int h = 0; h < 2; h++) {
            int c = h * 256 + t;                 // lds chunk id; dest = c*16 bytes
            int r = c >> 2;
            int g = (c & 3) ^ ((r >> 1) & 3);    // swizzled source k-group
            gld_lds16(A  + (size_t)(m0 + r) * K + k0 + g * 8, (char*)&lds[0][0] + c * 16);
            gld_lds16(Bm + (size_t)(n0 + r) * K + k0 + g * 8, (char*)&lds[1][0] + c * 16);
        }
        __syncthreads();

        bf16x8 av[4], bv[4];
        #pragma unroll
        for (int i = 0; i < 4; i++) {
            int ra = wr * 64 + i * 16 + fm;
            int rb = wc * 64 + i * 16 + fm;
            av[i] = *(const bf16x8*)&lds[0][ra * 32 + ((gf ^ ((ra >> 1) & 3)) * 8)];
            bv[i] = *(const bf16x8*)&lds[1][rb * 32 + ((gf ^ ((rb >> 1) & 3)) * 8)];
        }
        #pragma unroll
        for (int i = 0; i < 4; i++)
            #pragma unroll
            for (int j = 0; j < 4; j++)
                acc[i][j] = __builtin_amdgcn_mfma_f32_16x16x32_bf16(av[i], bv[j], acc[i][j], 0, 0, 0);
    }

    // epilogue: C/D layout col=lane&15, row=(lane>>4)*4+reg
    int cr = (lane >> 4) * 4;
    int cc = lane & 15;

    if (MODE == 0) {
        unsigned short* Co = (unsigned short*)Cg + (size_t)b * (size_t)N_ * N_;
        float lsev[4];
        #pragma unroll
        for (int j = 0; j < 4; j++) lsev[j] = lse[b * N_ + n0 + wc * 64 + j * 16 + cc];
        float rsum[16];
        #pragma unroll
        for (int q = 0; q < 16; q++) rsum[q] = 0.0f;
        #pragma unroll
        for (int i = 0; i < 4; i++) {
            #pragma unroll
            for (int r = 0; r < 4; r++) {
                int row = m0 + wr * 64 + i * 16 + cr + r;
                size_t ro = (size_t)row * N_;
                #pragma unroll
                for (int j = 0; j < 4; j++) {
                    int col = n0 + wc * 64 + j * 16 + cc;
                    float ev = __expf(acc[i][j][r] - lsev[j]);   // always in [e^-14, e^-1]
                    unsigned short eb = f2bf(ev);
                    union { unsigned u; float f; } bk; bk.u = ((unsigned)eb) << 16;
                    Co[ro + col] = eb;
                    rsum[i * 4 + r] += bk.f;                     // sum the ROUNDED value
                }
            }
        }
        #pragma unroll
        for (int q = 0; q < 16; q++) {
            float sv = rsum[q];
            sv += __shfl_xor(sv, 1, 64);
            sv += __shfl_xor(sv, 2, 64);
            sv += __shfl_xor(sv, 4, 64);
            sv += __shfl_xor(sv, 8, 64);
            rsum[q] = sv;
        }
        if (cc == 0) {
            #pragma unroll
            for (int q = 0; q < 16; q++) {
                int row = m0 + wr * 64 + (q >> 2) * 16 + cr + (q & 3);
                atomicAdd(&rowsum[b * N_ + row], rsum[q]);
            }
        }
    } else {
        float* Co = (float*)Cg + (size_t)b * (size_t)N_ * N_;
        #pragma unroll
        for (int i = 0; i < 4; i++) {
            #pragma unroll
            for (int r = 0; r < 4; r++) {
                int row = m0 + wr * 64 + i * 16 + cr + r;
                float inv = 1.0f / rowsum[b * N_ + row];
                size_t ro = (size_t)row * N_;
                #pragma unroll
                for (int j = 0; j < 4; j++) {
                    int col = n0 + wc * 64 + j * 16 + cc;
                    Co[ro + col] = acc[i][j][r] * inv;
                }
            }
        }
    }
}

// ---------------------------------------------------------------------------
// K3: bf16 transpose per batch: xb[b][j][d] -> xbT[b][d][j], 64x64 tiles.
// LDS stride 66 u16 = 33 words (1 mod 32) -> conflict-free reads & writes.
// ---------------------------------------------------------------------------
__global__ __launch_bounds__(256) void transpose_kernel(const unsigned short* __restrict__ in,
        unsigned short* __restrict__ out) {
    int b  = blockIdx.z;
    int j0 = blockIdx.y * 64;
    int d0 = blockIdx.x * 64;
    __shared__ unsigned short tile[64][66];
    const unsigned short* ip = in + ((size_t)b * N_ + j0) * D_ + d0;
    int t = threadIdx.x;
    #pragma unroll
    for (int c = t; c < 512; c += 256) {
        int r = c >> 3, col = (c & 7) * 8;
        uint4 val = *(const uint4*)(ip + (size_t)r * D_ + col);
        unsigned int* dst = (unsigned int*)&tile[r][col];   // 4-byte aligned
        dst[0] = val.x; dst[1] = val.y; dst[2] = val.z; dst[3] = val.w;
    }
    __syncthreads();
    unsigned short* op = out + ((size_t)b * D_ + d0) * N_ + j0;
    #pragma unroll
    for (int c = t; c < 512; c += 256) {
        int r = c >> 3, col = (c & 7) * 8;   // r = d within tile, col = j offset
        unsigned short vals[8];
        #pragma unroll
        for (int k = 0; k < 8; k++) vals[k] = tile[col + k][r];
        uint4 o;
        o.x = (unsigned)vals[0] | ((unsigned)vals[1] << 16);
        o.y = (unsigned)vals[2] | ((unsigned)vals[3] << 16);
        o.z = (unsigned)vals[4] | ((unsigned)vals[5] << 16);
        o.w = (unsigned)vals[6] | ((unsigned)vals[7] << 16);
        *(uint4*)(op + (size_t)r * N_ + col) = o;
    }
}

extern "C" void kernel_launch(void* const* d_in, const int* in_sizes, int n_in,
                              void* d_out, int out_size, void* d_ws, size_t ws_size,
                              hipStream_t stream) {
    const float* x = (const float*)d_in[0];
    float* out = (float*)d_out;
    char* ws = (char*)d_ws;

    // layout: [pb 64M][xb 64M][xbT 64M][attnE 64M][lse 128K][rowsum 128K]
    unsigned short* pb    = (unsigned short*)(ws);
    unsigned short* xb    = (unsigned short*)(ws + 67108864ULL);
    unsigned short* xbT   = (unsigned short*)(ws + 134217728ULL);
    unsigned short* attnE = (unsigned short*)(ws + 201326592ULL);
    float*          lse   = (float*)(ws + 268435456ULL);
    float*          rowsum= (float*)(ws + 268566528ULL);

    hipMemsetAsync(rowsum, 0, B_ * N_ * sizeof(float), stream);
    prep_kernel<<<dim3(B_ * N_ / 4), 256, 0, stream>>>(x, pb, xb, lse);
    transpose_kernel<<<dim3(16, 16, B_), 256, 0, stream>>>(xb, xbT);
    gemm_bt<0><<<dim3(8, 8, B_), 256, 0, stream>>>(pb, xb, attnE, lse, rowsum);
    gemm_bt<1><<<dim3(8, 8, B_), 256, 0, stream>>>(attnE, xbT, out, nullptr, rowsum);
}